// Round 2
// baseline (147.817 us; speedup 1.0000x reference)
//
#include <hip/hip_runtime.h>
#include <stdint.h>

#define V 50257
#define B_ 64
#define S_ 8
#define ROWS (B_ * S_)
#define L_ 2048
#define NEG_INF -1000000000.0f
#define MASK_WORDS_PER_B 1571   // ceil(50257/32)
#define MASK_WORDS_TOTAL (B_ * MASK_WORDS_PER_B)
#define CAND_CAP 4096
#define FIN_CAP 1024
#define TOP_CAP 64              // top-k=50 plus headroom for exact ties at kth
#define TOTAL (ROWS * V)        // 25,731,584
#define NVEC (TOTAL / 4)        // 6,432,896 (exact)

__device__ __forceinline__ unsigned fkey(float f) {
    unsigned u = __float_as_uint(f);
    return (u & 0x80000000u) ? ~u : (u | 0x80000000u);
}

__device__ __forceinline__ int blockReduceSum(int v, int tid, int* s4) {
#pragma unroll
    for (int off = 32; off; off >>= 1) v += __shfl_down(v, off);
    __syncthreads();
    if ((tid & 63) == 0) s4[tid >> 6] = v;
    __syncthreads();
    return s4[0] + s4[1] + s4[2] + s4[3];
}

__global__ __launch_bounds__(256) void zero_mask_kernel(unsigned* __restrict__ p, int n) {
    int i = blockIdx.x * 256 + threadIdx.x;
    if (i < n) p[i] = 0u;
}

__global__ __launch_bounds__(256) void build_mask_kernel(const int* __restrict__ ids,
                                                         unsigned* __restrict__ mask) {
    int i = blockIdx.x * 256 + threadIdx.x;
    if (i >= B_ * L_) return;
    int t = ids[i];
    int b = i >> 11;  // L_ = 2048
    atomicOr(&mask[b * MASK_WORDS_PER_B + (t >> 5)], 1u << (t & 31));
}

// One block per row. Reproduces reference semantics exactly, including fp32
// value ties: kth = 50th largest of x; kept set = ALL x >= kth (may exceed 50);
// stable descending sort by (value, token index) like np.argsort(-x); softmax +
// cumsum in f64 (true-valued decision); emit threshold value + tie-break index.
__global__ __launch_bounds__(256) void row_thresh_kernel(const float* __restrict__ logits,
                                                         float* __restrict__ rowThresh,
                                                         int* __restrict__ rowTie) {
    const int tid = threadIdx.x;
    const int row = blockIdx.x;
    if (row >= ROWS) return;
    const float* rp = logits + (size_t)row * V;

    __shared__ float candV[CAND_CAP];
    __shared__ int   candI[CAND_CAP];
    __shared__ float finV[FIN_CAP];
    __shared__ int   finI[FIN_CAP];
    __shared__ float sVal[TOP_CAP];
    __shared__ int   sIdx[TOP_CAP];
    __shared__ int s_cnt;
    __shared__ int s_red[4];

    const unsigned mis = (unsigned)(((size_t)row * (size_t)V) & 3u);
    const int a0 = (int)((4u - mis) & 3u);
    const int nv = (V - a0) >> 2;
    const int tailStart = a0 + (nv << 2);

    // Adaptive candidate gather on x = v/0.8: T=3.0 yields ~412/row for this
    // distribution; retry loop for robustness.
    float T = 3.0f;
    int cnt = 0;
    for (int attempt = 0; attempt < 12; ++attempt) {
        if (tid == 0) s_cnt = 0;
        __syncthreads();
        for (int i = tid; i < nv; i += 256) {
            float4 v = *reinterpret_cast<const float4*>(rp + a0 + (i << 2));
            float xs[4] = {v.x, v.y, v.z, v.w};
#pragma unroll
            for (int c = 0; c < 4; ++c) {
                float x = xs[c] / 0.8f;
                if (x >= T) {
                    int p = atomicAdd(&s_cnt, 1);
                    if (p < CAND_CAP) { candV[p] = x; candI[p] = a0 + (i << 2) + c; }
                }
            }
        }
        if (tid < a0) {
            float x = rp[tid] / 0.8f;
            if (x >= T) {
                int p = atomicAdd(&s_cnt, 1);
                if (p < CAND_CAP) { candV[p] = x; candI[p] = tid; }
            }
        }
        if (tid < V - tailStart) {
            float x = rp[tailStart + tid] / 0.8f;
            if (x >= T) {
                int p = atomicAdd(&s_cnt, 1);
                if (p < CAND_CAP) { candV[p] = x; candI[p] = tailStart + tid; }
            }
        }
        __syncthreads();
        cnt = s_cnt;
        if (cnt >= 50 && cnt <= CAND_CAP) break;
        if (cnt < 50) T -= 1.5f; else T += 1.5f;
        __syncthreads();
    }
    if (cnt > CAND_CAP) cnt = CAND_CAP;

    // Reduce to <= FIN_CAP finalists (rare path: key-space bisect for the 50th
    // largest key, compact everything >= it — keeps value-ties).
    const float* fV;
    const int* fI;
    int F;
    if (cnt <= FIN_CAP) {
        fV = candV; fI = candI; F = cnt;
    } else {
        unsigned lo = fkey(T);
        unsigned hi = 0xFFFFFFFFu;
        while (lo < hi) {
            unsigned mid = lo + ((hi - lo) >> 1) + 1u;
            int c = 0;
            for (int i = tid; i < cnt; i += 256) c += (int)(fkey(candV[i]) >= mid);
            c = blockReduceSum(c, tid, s_red);
            if (c >= 50) lo = mid; else hi = mid - 1u;
        }
        __syncthreads();
        if (tid == 0) s_cnt = 0;
        __syncthreads();
        for (int i = tid; i < cnt; i += 256) {
            if (fkey(candV[i]) >= lo) {
                int p = atomicAdd(&s_cnt, 1);
                if (p < FIN_CAP) { finV[p] = candV[i]; finI[p] = candI[i]; }
            }
        }
        __syncthreads();
        F = s_cnt < FIN_CAP ? s_cnt : FIN_CAP;
        fV = finV; fI = finI;
    }

    if (tid < TOP_CAP) { sVal[tid] = -3.4e38f; sIdx[tid] = 0x7FFFFFFF; }
    __syncthreads();

    // Rank-sort with np.argsort(-x)-equivalent stable order: key (value desc,
    // token index asc). Deterministic regardless of atomicAdd slot order.
    {
        float v0 = (tid < F) ? fV[tid] : -3.4e38f;
        float v1 = (tid + 256 < F) ? fV[tid + 256] : -3.4e38f;
        float v2 = (tid + 512 < F) ? fV[tid + 512] : -3.4e38f;
        float v3 = (tid + 768 < F) ? fV[tid + 768] : -3.4e38f;
        int i0 = (tid < F) ? fI[tid] : 0x7FFFFFFF;
        int i1 = (tid + 256 < F) ? fI[tid + 256] : 0x7FFFFFFF;
        int i2 = (tid + 512 < F) ? fI[tid + 512] : 0x7FFFFFFF;
        int i3 = (tid + 768 < F) ? fI[tid + 768] : 0x7FFFFFFF;
        int r0 = 0, r1 = 0, r2 = 0, r3 = 0;
        for (int j = 0; j < F; ++j) {
            float w = fV[j];
            int wi = fI[j];
            r0 += (w > v0) || (w == v0 && wi < i0);
            r1 += (w > v1) || (w == v1 && wi < i1);
            r2 += (w > v2) || (w == v2 && wi < i2);
            r3 += (w > v3) || (w == v3 && wi < i3);
        }
        if (tid < F && r0 < TOP_CAP) { sVal[r0] = v0; sIdx[r0] = i0; }
        if (tid + 256 < F && r1 < TOP_CAP) { sVal[r1] = v1; sIdx[r1] = i1; }
        if (tid + 512 < F && r2 < TOP_CAP) { sVal[r2] = v2; sIdx[r2] = i2; }
        if (tid + 768 < F && r3 < TOP_CAP) { sVal[r3] = v3; sIdx[r3] = i3; }
    }
    __syncthreads();

    if (tid == 0) {
        // kth = 50th largest value; kept set = all x >= kth (ties included).
        float kth = sVal[49];
        int M = 50;
        while (M < TOP_CAP && sVal[M] == kth) ++M;
        // f64 softmax + cumsum over the M kept entries (entries beyond M
        // contribute exp(-1e9 - m) == 0 in the fp32 reference).
        double m = (double)sVal[0];
        double denom = 0.0;
#pragma unroll 1
        for (int i = 0; i < M; ++i) denom += exp((double)sVal[i] - m);
        double cum = 0.0;
        int J = M - 1;
#pragma unroll 1
        for (int i = 0; i < M; ++i) {
            cum += exp((double)sVal[i] - m) / denom;
            if (cum > 0.9) { J = i; break; }
        }
        rowThresh[row] = sVal[J];
        rowTie[row] = sIdx[J];   // among x == thresh, keep token index <= this
    }
}

__global__ __launch_bounds__(256) void apply_kernel(const float4* __restrict__ in4,
                                                    const float* __restrict__ rowThresh,
                                                    const int* __restrict__ rowTie,
                                                    const unsigned* __restrict__ mask,
                                                    float4* __restrict__ out4) {
    int idx = blockIdx.x * 256 + threadIdx.x;
    if (idx >= NVEC) return;
    unsigned e = (unsigned)idx << 2;
    unsigned row = e / (unsigned)V;          // magic-mul
    unsigned rem = e - row * (unsigned)V;
    float4 v = in4[idx];
    float xs[4] = {v.x, v.y, v.z, v.w};
    float o[4];
    float t0 = rowThresh[row];
    int ti0 = rowTie[row];
    bool crosses = (rem + 3u >= (unsigned)V);
    float t1 = crosses ? rowThresh[row + 1] : t0;
    int ti1 = crosses ? rowTie[row + 1] : ti0;
#pragma unroll
    for (int c = 0; c < 4; ++c) {
        unsigned tok = rem + (unsigned)c;
        unsigned r = row;
        float t = t0;
        int ti = ti0;
        if (tok >= (unsigned)V) { tok -= (unsigned)V; r = row + 1u; t = t1; ti = ti1; }
        float x = xs[c] / 0.8f;
        bool keep = (x > t) || (x == t && (int)tok <= ti);
        float oo = keep ? x : NEG_INF;
        if ((r & 7u) == 7u) {
            unsigned w = mask[(r >> 3) * MASK_WORDS_PER_B + (tok >> 5)];
            if ((w >> (tok & 31u)) & 1u) oo = (oo < 0.0f) ? oo * 1.2f : oo / 1.2f;
        }
        o[c] = oo;
    }
    out4[idx] = make_float4(o[0], o[1], o[2], o[3]);
}

extern "C" void kernel_launch(void* const* d_in, const int* in_sizes, int n_in,
                              void* d_out, int out_size, void* d_ws, size_t ws_size,
                              hipStream_t stream) {
    const float* logits = (const float*)d_in[0];
    const int* ids = (const int*)d_in[1];
    float* out = (float*)d_out;

    // ws layout: [0,4K) rowThresh (512 f32 + pad); [4K,8K) rowTie (512 i32 + pad);
    // [8K, ...) presence bitmask (64 x 1571 words = 402,176 B)
    float* rowThresh = (float*)d_ws;
    int* rowTie = (int*)((char*)d_ws + 4096);
    unsigned* mask = (unsigned*)((char*)d_ws + 8192);

    zero_mask_kernel<<<(MASK_WORDS_TOTAL + 255) / 256, 256, 0, stream>>>(mask, MASK_WORDS_TOTAL);
    build_mask_kernel<<<(B_ * L_) / 256, 256, 0, stream>>>(ids, mask);
    row_thresh_kernel<<<ROWS, 256, 0, stream>>>(logits, rowThresh, rowTie);
    apply_kernel<<<(NVEC + 255) / 256, 256, 0, stream>>>((const float4*)logits, rowThresh, rowTie,
                                                         mask, (float4*)out);
}

// Round 3
// 125.805 us; speedup vs baseline: 1.1750x; 1.1750x over previous
//
#include <hip/hip_runtime.h>
#include <stdint.h>

#define V 50257
#define B_ 64
#define S_ 8
#define ROWS (B_ * S_)
#define L_ 2048
#define NEG_INF -1000000000.0f
#define MASK_WORDS_PER_B 1571   // ceil(50257/32)
#define MASK_WORDS_TOTAL (B_ * MASK_WORDS_PER_B)
#define CAND_CAP 4096
#define FIN_CAP 1024
#define TOP_CAP 64              // top-k=50 plus headroom for exact ties at kth
#define TOTAL (ROWS * V)        // 25,731,584
#define NVEC (TOTAL / 4)        // 6,432,896 (exact)
#define RT_THREADS 1024

__device__ __forceinline__ unsigned fkey(float f) {
    unsigned u = __float_as_uint(f);
    return (u & 0x80000000u) ? ~u : (u | 0x80000000u);
}

__device__ __forceinline__ int blockReduceSum(int v, int tid, int* s16) {
#pragma unroll
    for (int off = 32; off; off >>= 1) v += __shfl_down(v, off);
    __syncthreads();
    if ((tid & 63) == 0) s16[tid >> 6] = v;
    __syncthreads();
    int t = 0;
#pragma unroll
    for (int k = 0; k < RT_THREADS / 64; ++k) t += s16[k];
    return t;
}

__global__ __launch_bounds__(256) void zero_mask_kernel(unsigned* __restrict__ p, int n) {
    int i = blockIdx.x * 256 + threadIdx.x;
    if (i < n) p[i] = 0u;
}

__global__ __launch_bounds__(256) void build_mask_kernel(const int* __restrict__ ids,
                                                         unsigned* __restrict__ mask) {
    int i = blockIdx.x * 256 + threadIdx.x;
    if (i >= B_ * L_) return;
    int t = ids[i];
    int b = i >> 11;  // L_ = 2048
    atomicOr(&mask[b * MASK_WORDS_PER_B + (t >> 5)], 1u << (t & 31));
}

// One 1024-thread block per row. Exact reference semantics incl. fp32 ties:
// kth = 50th largest of x=v/0.8; kept = ALL x >= kth; stable (value desc, index
// asc) order like np.argsort(-x); f64 softmax+cumsum decision; emit
// (threshold value, tie-break index).
__global__ __launch_bounds__(RT_THREADS, 8) void row_thresh_kernel(
        const float* __restrict__ logits, float* __restrict__ rowThresh,
        int* __restrict__ rowTie) {
    const int tid = threadIdx.x;
    const int row = blockIdx.x;
    if (row >= ROWS) return;
    const float* rp = logits + (size_t)row * V;

    __shared__ float candV[CAND_CAP];
    __shared__ int   candI[CAND_CAP];
    __shared__ float finV[FIN_CAP];
    __shared__ int   finI[FIN_CAP];
    __shared__ float sVal[TOP_CAP];
    __shared__ int   sIdx[TOP_CAP];
    __shared__ double sExp[TOP_CAP];
    __shared__ int s_cnt, s_M;
    __shared__ int s_red[RT_THREADS / 64];

    const unsigned mis = (unsigned)(((size_t)row * (size_t)V) & 3u);
    const int a0 = (int)((4u - mis) & 3u);
    const int nv = (V - a0) >> 2;                 // ~12564 float4s
    const int tailStart = a0 + (nv << 2);
    const float4* vp = reinterpret_cast<const float4*>(rp + a0);

    // Candidate predicate on RAW values: v >= TR (TR = 3.0*0.8 = 2.4 exactly in
    // fp32). No division in the hot loop; x = v/0.8f computed only on stores.
    // Monotone v->x plus count>=50 guarantees the candidate set contains the
    // top-50 (incl. all value ties at kth). Retry loop for generic robustness.
    float TR = 2.4f;
    int cnt = 0;
    for (int attempt = 0; attempt < 12; ++attempt) {
        if (tid == 0) s_cnt = 0;
        __syncthreads();
        // Unroll-4 with clamped (always-issued) loads for memory-level parallelism.
        for (int base = tid; base < nv; base += 4 * RT_THREADS) {
            int i1 = base + RT_THREADS, i2 = base + 2 * RT_THREADS, i3 = base + 3 * RT_THREADS;
            float4 a = vp[base];
            float4 b = vp[i1 < nv ? i1 : nv - 1];
            float4 c = vp[i2 < nv ? i2 : nv - 1];
            float4 d = vp[i3 < nv ? i3 : nv - 1];
            float va[16] = {a.x, a.y, a.z, a.w, b.x, b.y, b.z, b.w,
                            c.x, c.y, c.z, c.w, d.x, d.y, d.z, d.w};
            int ib[4] = {base, i1, i2, i3};
            bool ok[4] = {true, i1 < nv, i2 < nv, i3 < nv};
#pragma unroll
            for (int q = 0; q < 4; ++q) {
                if (!ok[q]) continue;
#pragma unroll
                for (int cc = 0; cc < 4; ++cc) {
                    float v = va[q * 4 + cc];
                    if (v >= TR) {
                        int p = atomicAdd(&s_cnt, 1);
                        if (p < CAND_CAP) { candV[p] = v / 0.8f; candI[p] = a0 + (ib[q] << 2) + cc; }
                    }
                }
            }
        }
        if (tid < a0) {
            float v = rp[tid];
            if (v >= TR) {
                int p = atomicAdd(&s_cnt, 1);
                if (p < CAND_CAP) { candV[p] = v / 0.8f; candI[p] = tid; }
            }
        }
        if (tid < V - tailStart) {
            float v = rp[tailStart + tid];
            if (v >= TR) {
                int p = atomicAdd(&s_cnt, 1);
                if (p < CAND_CAP) { candV[p] = v / 0.8f; candI[p] = tailStart + tid; }
            }
        }
        __syncthreads();
        cnt = s_cnt;
        if (cnt >= 50 && cnt <= CAND_CAP) break;   // retry keeps candidate set deterministic
        if (cnt < 50) TR -= 1.2f; else TR += 1.2f;
        __syncthreads();
    }
    if (cnt > CAND_CAP) cnt = CAND_CAP;

    // Reduce to <= FIN_CAP finalists (rare path: key-space bisect for the 50th
    // largest key, compact everything >= it — keeps value ties).
    const float* fV;
    const int* fI;
    int F;
    if (cnt <= FIN_CAP) {
        fV = candV; fI = candI; F = cnt;
    } else {
        unsigned lo = fkey(TR / 0.8f) - 1u;  // conservative floor in x-key space
        unsigned hi = 0xFFFFFFFFu;
        while (lo < hi) {
            unsigned mid = lo + ((hi - lo) >> 1) + 1u;
            int c = 0;
            for (int i = tid; i < cnt; i += RT_THREADS) c += (int)(fkey(candV[i]) >= mid);
            c = blockReduceSum(c, tid, s_red);
            if (c >= 50) lo = mid; else hi = mid - 1u;
        }
        __syncthreads();
        if (tid == 0) s_cnt = 0;
        __syncthreads();
        for (int i = tid; i < cnt; i += RT_THREADS) {
            if (fkey(candV[i]) >= lo) {
                int p = atomicAdd(&s_cnt, 1);
                if (p < FIN_CAP) { finV[p] = candV[i]; finI[p] = candI[i]; }
            }
        }
        __syncthreads();
        F = s_cnt < FIN_CAP ? s_cnt : FIN_CAP;
        fV = finV; fI = finI;
    }

    if (tid < TOP_CAP) { sVal[tid] = -3.4e38f; sIdx[tid] = 0x7FFFFFFF; }
    __syncthreads();

    // Rank-sort (one candidate per thread; F <= 1024 = blockDim). LDS broadcast
    // reads are conflict-free. Stable key: (value desc, token index asc).
    {
        float v0 = (tid < F) ? fV[tid] : -3.4e38f;
        int i0 = (tid < F) ? fI[tid] : 0x7FFFFFFF;
        int r0 = 0;
        for (int j = 0; j < F; ++j) {
            float w = fV[j];
            int wi = fI[j];
            r0 += (w > v0) || (w == v0 && wi < i0);
        }
        if (tid < F && r0 < TOP_CAP) { sVal[r0] = v0; sIdx[r0] = i0; }
    }
    __syncthreads();

    if (tid == 0) {
        float kth = sVal[49];
        int M = 50;
        while (M < TOP_CAP && sVal[M] == kth) ++M;   // include exact ties at kth
        s_M = M;
    }
    __syncthreads();
    int M = s_M;
    if (tid < M) sExp[tid] = exp((double)sVal[tid] - (double)sVal[0]);
    __syncthreads();

    if (tid == 0) {
        double denom = 0.0;
#pragma unroll 1
        for (int i = 0; i < M; ++i) denom += sExp[i];
        double cum = 0.0;
        int J = M - 1;
#pragma unroll 1
        for (int i = 0; i < M; ++i) {
            cum += sExp[i] / denom;
            if (cum > 0.9) { J = i; break; }
        }
        rowThresh[row] = sVal[J];
        rowTie[row] = sIdx[J];   // among x == thresh, keep token index <= this
    }
}

__global__ __launch_bounds__(256) void apply_kernel(const float4* __restrict__ in4,
                                                    const float* __restrict__ rowThresh,
                                                    const int* __restrict__ rowTie,
                                                    const unsigned* __restrict__ mask,
                                                    float4* __restrict__ out4) {
    int idx = blockIdx.x * 256 + threadIdx.x;
    if (idx >= NVEC) return;
    unsigned e = (unsigned)idx << 2;
    unsigned row = e / (unsigned)V;          // magic-mul
    unsigned rem = e - row * (unsigned)V;
    float4 v = in4[idx];
    float xs[4] = {v.x, v.y, v.z, v.w};
    float o[4];
    float t0 = rowThresh[row];
    int ti0 = rowTie[row];
    bool crosses = (rem + 3u >= (unsigned)V);
    float t1 = crosses ? rowThresh[row + 1] : t0;
    int ti1 = crosses ? rowTie[row + 1] : ti0;
#pragma unroll
    for (int c = 0; c < 4; ++c) {
        unsigned tok = rem + (unsigned)c;
        unsigned r = row;
        float t = t0;
        int ti = ti0;
        if (tok >= (unsigned)V) { tok -= (unsigned)V; r = row + 1u; t = t1; ti = ti1; }
        float x = xs[c] / 0.8f;
        bool keep = (x > t) || (x == t && (int)tok <= ti);
        float oo = keep ? x : NEG_INF;
        if ((r & 7u) == 7u) {
            unsigned w = mask[(r >> 3) * MASK_WORDS_PER_B + (tok >> 5)];
            if ((w >> (tok & 31u)) & 1u) oo = (oo < 0.0f) ? oo * 1.2f : oo / 1.2f;
        }
        o[c] = oo;
    }
    out4[idx] = make_float4(o[0], o[1], o[2], o[3]);
}

extern "C" void kernel_launch(void* const* d_in, const int* in_sizes, int n_in,
                              void* d_out, int out_size, void* d_ws, size_t ws_size,
                              hipStream_t stream) {
    const float* logits = (const float*)d_in[0];
    const int* ids = (const int*)d_in[1];
    float* out = (float*)d_out;

    // ws layout: [0,4K) rowThresh (512 f32 + pad); [4K,8K) rowTie (512 i32 + pad);
    // [8K, ...) presence bitmask (64 x 1571 words = 402,176 B)
    float* rowThresh = (float*)d_ws;
    int* rowTie = (int*)((char*)d_ws + 4096);
    unsigned* mask = (unsigned*)((char*)d_ws + 8192);

    zero_mask_kernel<<<(MASK_WORDS_TOTAL + 255) / 256, 256, 0, stream>>>(mask, MASK_WORDS_TOTAL);
    build_mask_kernel<<<(B_ * L_) / 256, 256, 0, stream>>>(ids, mask);
    row_thresh_kernel<<<ROWS, RT_THREADS, 0, stream>>>(logits, rowThresh, rowTie);
    apply_kernel<<<(NVEC + 255) / 256, 256, 0, stream>>>((const float4*)logits, rowThresh, rowTie,
                                                         mask, (float4*)out);
}